// Round 8
// baseline (598.059 us; speedup 1.0000x reference)
//
#include <hip/hip_runtime.h>

typedef unsigned short u16;
typedef unsigned int u32;
typedef __bf16 bf16_t;
typedef bf16_t bf16x8 __attribute__((ext_vector_type(8)));
typedef float floatx4 __attribute__((ext_vector_type(4)));

__device__ __forceinline__ float bf2f(u16 h) {
    union { unsigned u; float f; } v;
    v.u = ((unsigned)h) << 16;
    return v.f;
}

__device__ __forceinline__ u16 f2bf(float f) {
    union { float f; unsigned u; } v;
    v.f = f;
    unsigned r = v.u + 0x7fffu + ((v.u >> 16) & 1u);
    return (u16)(r >> 16);
}

// async global->LDS, 16B per lane. LDS dest = uniform base + lane*16 (HW rule).
typedef __attribute__((address_space(1))) const u32 gu32;
typedef __attribute__((address_space(3))) u32 lu32;
__device__ __forceinline__ void gload16(const void* g, void* l) {
    __builtin_amdgcn_global_load_lds((gu32*)g, (lu32*)l, 16, 0, 0);
}

// ---------------------------------------------------------------------------
// Weight transposes: fp32 in -> bf16 transposed out (tiny, L2-resident)
// scale folds the attention 1/sqrt(S) into Wq at transpose time.
// ---------------------------------------------------------------------------
__global__ void transpose_one(const float* __restrict__ W, u16* __restrict__ Wt,
                              int K, int N, float scale) {
    int idx = blockIdx.x * 256 + threadIdx.x;
    if (idx >= K * N) return;
    int nrow = idx / K;
    int k = idx - nrow * K;
    Wt[idx] = f2bf(W[k * N + nrow] * scale);   // Wt[n][k] = W[k][n] * scale
}

// WkvT [1024][768]: rows 0..511 = Wk^T, rows 512..1023 = Wv^T
__global__ void transpose_kv(const float* __restrict__ Wk, const float* __restrict__ Wv,
                             u16* __restrict__ Wt) {
    int idx = blockIdx.x * 256 + threadIdx.x;
    if (idx >= 1024 * 768) return;
    int nrow = idx / 768;
    int k = idx - nrow * 768;
    Wt[idx] = f2bf((nrow < 512) ? Wk[k * 512 + nrow] : Wv[k * 512 + (nrow - 512)]);
}

// V^T for attention: vt[((n*8+h)*64+s)*96 + c] = v[n][c][h][s], zero c>=77.
__global__ void transpose_v(const u16* __restrict__ kv, u16* __restrict__ vt) {
    int idx = blockIdx.x * 256 + threadIdx.x;
    if (idx >= 16 * 8 * 64 * 96) return;
    int c  = idx % 96;
    int t1 = idx / 96;
    int s  = t1 & 63;
    int t2 = t1 >> 6;
    int h  = t2 & 7;
    int n  = t2 >> 3;
    u16 val = 0;
    if (c < 77) val = kv[((long)(n * 77 + c)) * 1024 + 512 + h * 64 + s];
    vt[idx] = val;
}

// ---------------------------------------------------------------------------
// gemm_direct: C[M,N] = A[M,K] * Bt[N,K]^T (+bias) with NO LDS, NO barriers.
// Every wave loads its MFMA fragments straight from global memory:
//   A frag: row bm+wm+i*16+l16, 16B(bf16)/32B(fp32) at col k0+quad*8
//           -> wave instr touches 16 rows x 128B contiguous (coalesced).
//   B frag: row bn+wn+j*16+l16 of Bt (L2-resident weight), same pattern.
// Fragment re-reads (A x4 by N-waves, B x2 by M-waves) are served by L1/L2.
// Rationale: all LDS-staged variants sat at MfmaUtil ~14% with every pipe
// idle -- the block-wide barrier pair coupled 8 waves to the slowest staging
// chain. With zero barriers the compiler pipelines loads across K-steps and
// 16 waves/CU of free-running TLP hides latency.
// Requires: M%128==0, N%256==0, K%32==0, gridDim.x%8==0.
// ---------------------------------------------------------------------------
template <bool A_F32, bool OUT_F32>
__global__ __launch_bounds__(512, 4) void gemm_direct(
    const void* __restrict__ A_, const u16* __restrict__ Bt,
    void* __restrict__ C_, const float* __restrict__ bias,
    int M, int K, int N, int ntl2)
{
    const int tid  = threadIdx.x;
    const int lane = tid & 63;
    const int wave = tid >> 6;          // 0..7
    const int quad = lane >> 4;
    const int l16  = lane & 15;
    const int wm   = (wave & 1) * 64;   // 2 M-waves
    const int wn   = (wave >> 1) * 64;  // 4 N-waves

    // XCD-aware bijective swizzle (nwg % 8 == 0), N-tile fastest within XCD
    // so the 2 blocks sharing an A-panel land on the same XCD's L2.
    const int nwg = gridDim.x;
    const int wg  = blockIdx.x;
    const int t   = (wg & 7) * (nwg >> 3) + (wg >> 3);
    const long bm = (long)(t >> ntl2) * 128;
    const long bn = (long)(t & ((1 << ntl2) - 1)) * 256;

    const float* Af = (const float*)A_;
    const u16*   Ab = (const u16*)A_;

    // Per-fragment row bases (loop-invariant).
    long arow[4], brow[4];
    #pragma unroll
    for (int i = 0; i < 4; ++i)
        arow[i] = (bm + wm + i * 16 + l16) * (long)K + quad * 8;
    #pragma unroll
    for (int j = 0; j < 4; ++j)
        brow[j] = (bn + wn + j * 16 + l16) * (long)K + quad * 8;

    floatx4 acc[4][4] = {};

    #pragma unroll 2
    for (int k0 = 0; k0 < K; k0 += 32) {
        bf16x8 af[4], bfr[4];
        #pragma unroll
        for (int i = 0; i < 4; ++i) {
            if (A_F32) {
                const float* ap = Af + arow[i] + k0;
                float4 f0 = *(const float4*)ap;
                float4 f1 = *(const float4*)(ap + 4);
                union { bf16_t h[8]; bf16x8 v; } pk;
                pk.h[0] = (bf16_t)f0.x; pk.h[1] = (bf16_t)f0.y;
                pk.h[2] = (bf16_t)f0.z; pk.h[3] = (bf16_t)f0.w;
                pk.h[4] = (bf16_t)f1.x; pk.h[5] = (bf16_t)f1.y;
                pk.h[6] = (bf16_t)f1.z; pk.h[7] = (bf16_t)f1.w;
                af[i] = pk.v;
            } else {
                af[i] = *(const bf16x8*)(Ab + arow[i] + k0);
            }
        }
        #pragma unroll
        for (int j = 0; j < 4; ++j)
            bfr[j] = *(const bf16x8*)(Bt + brow[j] + k0);
        #pragma unroll
        for (int i = 0; i < 4; ++i)
            #pragma unroll
            for (int j = 0; j < 4; ++j)
                acc[i][j] = __builtin_amdgcn_mfma_f32_16x16x32_bf16(
                    af[i], bfr[j], acc[i][j], 0, 0, 0);
    }

    #pragma unroll
    for (int i = 0; i < 4; ++i) {
        #pragma unroll
        for (int r = 0; r < 4; ++r) {
            long row = bm + wm + i * 16 + quad * 4 + r;
            #pragma unroll
            for (int j = 0; j < 4; ++j) {
                long col = bn + wn + j * 16 + l16;
                float val = acc[i][j][r];
                if (bias) val += bias[col];
                if (OUT_F32) ((float*)C_)[row * N + col] = val;
                else         ((u16*)C_)[row * N + col] = f2bf(val);
            }
        }
    }
}

// ---------------------------------------------------------------------------
// GEMM (round-4 proven): LDS-staged, counted-vmcnt pipeline. Kept for the
// small kv projection (M=1232 needs row clamping; not worth a new path).
// ---------------------------------------------------------------------------
#define TM 128
#define TN 256
#define TK 32

template <bool A_F32, bool OUT_F32>
__global__ __launch_bounds__(512, 4) void gemm_bt(
    const void* __restrict__ A_, const u16* __restrict__ Bt,
    void* __restrict__ C_, const float* __restrict__ bias,
    int M, int K, int N, int ntl2)
{
    constexpr int AB = A_F32 ? TM * TK * 4 : TM * TK * 2;
    constexpr int BB = TN * TK * 2;
    __shared__ __align__(16) char smem[2 * (AB + BB)];

    const int tid  = threadIdx.x;
    const int lane = tid & 63;
    const int wave = tid >> 6;
    const int quad = lane >> 4;
    const int l16  = lane & 15;
    const int wm   = (wave & 1) * 64;
    const int wn   = (wave >> 1) * 64;

    const int nwg = gridDim.x;
    const int wg  = blockIdx.x;
    const int t   = (wg & 7) * (nwg >> 3) + (wg >> 3);
    const long bm = (long)(t >> ntl2) * TM;
    const long bn = (long)(t & ((1 << ntl2) - 1)) * TN;

    const float* Af = (const float*)A_;
    const u16*   Ab = (const u16*)A_;
    const long   Mm1 = (long)M - 1;

    floatx4 acc[4][4] = {};

    auto stage = [&](int b, int k0) {
        char* Abase = smem + b * (AB + BB);
        u16*  Bb    = (u16*)(Abase + AB);
        #pragma unroll
        for (int p = 0; p < 2; ++p) {
            int ch  = p * 512 + tid;
            int row = ch >> 2;
            int pc  = (ch & 3) ^ ((row >> 1) & 3);
            gload16(Bt + (bn + row) * K + k0 + pc * 8,
                    Bb + (p * 512 + wave * 64) * 8);
        }
        if (A_F32) {
            #pragma unroll
            for (int p = 0; p < 2; ++p) {
                int ch  = p * 512 + tid;
                int row = ch >> 3;
                int pcs = (ch & 7) ^ (row & 7);
                long gr = bm + row; if (gr > Mm1) gr = Mm1;
                gload16(Af + gr * K + k0 + pcs * 4,
                        (float*)Abase + (p * 512 + wave * 64) * 4);
            }
        } else {
            int row = tid >> 2;
            int pc  = (tid & 3) ^ ((row >> 1) & 3);
            long gr = bm + row; if (gr > Mm1) gr = Mm1;
            gload16(Ab + gr * K + k0 + pc * 8,
                    (u16*)Abase + (wave * 64) * 8);
        }
    };

    const int nk = K / TK;
    stage(0, 0);

    for (int tt = 0; tt < nk; ++tt) {
        const int cb = tt & 1;
        if (tt + 1 < nk) {
            stage(cb ^ 1, (tt + 1) * TK);
            if (A_F32) asm volatile("s_waitcnt vmcnt(4)" ::: "memory");
            else       asm volatile("s_waitcnt vmcnt(3)" ::: "memory");
        } else {
            asm volatile("s_waitcnt vmcnt(0)" ::: "memory");
        }
        __builtin_amdgcn_s_barrier();
        __builtin_amdgcn_sched_barrier(0);

        const char* Abase = smem + cb * (AB + BB);
        const u16*  Bb    = (const u16*)(Abase + AB);

        bf16x8 af[4], bfr[4];
        #pragma unroll
        for (int i = 0; i < 4; ++i) {
            int row = wm + i * 16 + l16;
            if (A_F32) {
                const char* arow = Abase + (size_t)row * 128;
                int x = row & 7;
                float4 f0 = *(const float4*)(arow + (((quad * 2)     ^ x) * 16));
                float4 f1 = *(const float4*)(arow + (((quad * 2 + 1) ^ x) * 16));
                union { bf16_t h[8]; bf16x8 v; } pk;
                pk.h[0] = (bf16_t)f0.x; pk.h[1] = (bf16_t)f0.y;
                pk.h[2] = (bf16_t)f0.z; pk.h[3] = (bf16_t)f0.w;
                pk.h[4] = (bf16_t)f1.x; pk.h[5] = (bf16_t)f1.y;
                pk.h[6] = (bf16_t)f1.z; pk.h[7] = (bf16_t)f1.w;
                af[i] = pk.v;
            } else {
                int pcs = quad ^ ((row >> 1) & 3);
                af[i] = *(const bf16x8*)((const u16*)Abase + row * 32 + pcs * 8);
            }
        }
        #pragma unroll
        for (int j = 0; j < 4; ++j) {
            int row = wn + j * 16 + l16;
            int pcs = quad ^ ((row >> 1) & 3);
            bfr[j] = *(const bf16x8*)(Bb + row * 32 + pcs * 8);
        }
        #pragma unroll
        for (int i = 0; i < 4; ++i)
            #pragma unroll
            for (int j = 0; j < 4; ++j)
                acc[i][j] = __builtin_amdgcn_mfma_f32_16x16x32_bf16(
                    af[i], bfr[j], acc[i][j], 0, 0, 0);

        __builtin_amdgcn_s_barrier();
    }

    #pragma unroll
    for (int i = 0; i < 4; ++i) {
        #pragma unroll
        for (int r = 0; r < 4; ++r) {
            long row = bm + wm + i * 16 + quad * 4 + r;
            if (row >= M) continue;
            #pragma unroll
            for (int j = 0; j < 4; ++j) {
                long col = bn + wn + j * 16 + l16;
                float val = acc[i][j][r];
                if (bias) val += bias[col];
                if (OUT_F32) ((float*)C_)[row * N + col] = val;
                else         ((u16*)C_)[row * N + col] = f2bf(val);
            }
        }
    }
}

// ---------------------------------------------------------------------------
// Fused attention v5 (round-7, kept). Barrier-free main body, coalesced
// 16B output stores via per-wave LDS scratch, setprio around MFMA clusters.
// ---------------------------------------------------------------------------
__global__ __launch_bounds__(512, 4) void attn_kernel(
    const u16* __restrict__ qb,   // [N, 4096, 512] bf16 (scores pre-scaled)
    const u16* __restrict__ kvb,  // [N*77, 1024] bf16 (cols 0..511 k)
    const u16* __restrict__ vt,   // [(n*8+h)*64+s][96] bf16, zero c>=77
    u16* __restrict__ ob)         // [N, 4096, 512] bf16
{
    const int QL = 4096, HS = 512;
    const int q0 = blockIdx.x * 256;
    const int h  = blockIdx.y;
    const int n  = blockIdx.z;

    __shared__ u16 ks [80 * 72];        // K [c][s], c zero-padded to 80
    __shared__ u16 vts[64 * 104];       // V^T [s][c], cols zero-padded to 96
    __shared__ u16 pS [8][32 * 104];    // per-wave P / output scratch

    const int tid  = threadIdx.x;
    const int lane = tid & 63;
    const int wave = tid >> 6;          // 0..7
    const int quad = lane >> 4;
    const int l16  = lane & 15;

    // ---- issue Q fragment loads first (hide under K/V staging) ----
    const long qrow = (long)n * QL + q0 + wave * 32;
    bf16x8 aq[2][2];
    #pragma unroll
    for (int t = 0; t < 2; ++t)
        #pragma unroll
        for (int kk = 0; kk < 2; ++kk)
            aq[t][kk] = *(const bf16x8*)(
                qb + (qrow + t * 16 + l16) * HS + h * 64 + kk * 32 + quad * 8);

    // ---- stage K rows (coalesced, zero-pad c>=77) ----
    const u16* kbase = kvb + (long)n * 77 * 1024 + h * 64;
    for (int v = tid; v < 640; v += 512) {
        int c = v >> 3, g = (v & 7) * 8;
        uint4 val = make_uint4(0, 0, 0, 0);
        if (c < 77) val = *(const uint4*)(kbase + (long)c * 1024 + g);
        *(uint4*)(&ks[c * 72 + g]) = val;
    }
    // ---- stage V^T rows from vt_ws ----
    const u16* vtbase = vt + (long)((n * 8 + h) * 64) * 96;
    for (int v = tid; v < 768; v += 512) {           // 64 rows x 12 uint4
        int r = v / 12, c8 = v - r * 12;
        *(uint4*)(&vts[r * 104 + c8 * 8]) = *(const uint4*)(vtbase + v * 8);
    }
    __syncthreads();    // the ONLY block-wide barrier

    // ---- QK^T: wave's 32 rows x 80 cols (2 row-tiles x 5 col-tiles) ----
    floatx4 accS[2][5] = {};
    #pragma unroll
    for (int kk = 0; kk < 2; ++kk) {
        bf16x8 bk[5];
        #pragma unroll
        for (int j = 0; j < 5; ++j)
            bk[j] = *(const bf16x8*)(&ks[(j * 16 + l16) * 72 + kk * 32 + quad * 8]);
        __builtin_amdgcn_s_setprio(1);
        #pragma unroll
        for (int t = 0; t < 2; ++t)
            #pragma unroll
            for (int j = 0; j < 5; ++j)
                accS[t][j] = __builtin_amdgcn_mfma_f32_16x16x32_bf16(
                    aq[t][kk], bk[j], accS[t][j], 0, 0, 0);
        __builtin_amdgcn_s_setprio(0);
    }

    // ---- softmax in registers; write P rows into private LDS ----
    const bool v4ok = (l16 < 13);       // col 64+l16 valid iff < 77
    u16* pw = pS[wave];
    #pragma unroll
    for (int t = 0; t < 2; ++t) {
        #pragma unroll
        for (int r = 0; r < 4; ++r) {
            float v0 = accS[t][0][r];
            float v1 = accS[t][1][r];
            float v2 = accS[t][2][r];
            float v3 = accS[t][3][r];
            float v4 = v4ok ? accS[t][4][r] : -1e30f;
            float mx = fmaxf(fmaxf(fmaxf(v0, v1), fmaxf(v2, v3)), v4);
            mx = fmaxf(mx, __shfl_xor(mx, 1));
            mx = fmaxf(mx, __shfl_xor(mx, 2));
            mx = fmaxf(mx, __shfl_xor(mx, 4));
            mx = fmaxf(mx, __shfl_xor(mx, 8));
            float e0 = __expf(v0 - mx), e1 = __expf(v1 - mx);
            float e2 = __expf(v2 - mx), e3 = __expf(v3 - mx);
            float e4 = __expf(v4 - mx);
            float sum = e0 + e1 + e2 + e3 + e4;
            sum += __shfl_xor(sum, 1);
            sum += __shfl_xor(sum, 2);
            sum += __shfl_xor(sum, 4);
            sum += __shfl_xor(sum, 8);
            float inv = 1.f / sum;
            int row = t * 16 + quad * 4 + r;
            pw[row * 104 +  0 + l16] = f2bf(e0 * inv);
            pw[row * 104 + 16 + l16] = f2bf(e1 * inv);
            pw[row * 104 + 32 + l16] = f2bf(e2 * inv);
            pw[row * 104 + 48 + l16] = f2bf(e3 * inv);
            pw[row * 104 + 64 + l16] = f2bf(e4 * inv);
            pw[row * 104 + 80 + l16] = 0;
        }
    }
    // (same-wave ds_write -> ds_read ordered by lgkmcnt; LDS ops are in-order)

    // ---- PV: out[32,64] = P[32,96] @ V[96,64] ----
    floatx4 accO[2][4] = {};
    #pragma unroll
    for (int kk = 0; kk < 3; ++kk) {
        bf16x8 aw[2], bv[4];
        #pragma unroll
        for (int t = 0; t < 2; ++t)
            aw[t] = *(const bf16x8*)(&pw[(t * 16 + l16) * 104 + kk * 32 + quad * 8]);
        #pragma unroll
        for (int j = 0; j < 4; ++j)
            bv[j] = *(const bf16x8*)(&vts[(j * 16 + l16) * 104 + kk * 32 + quad * 8]);
        __builtin_amdgcn_s_setprio(1);
        #pragma unroll
        for (int t = 0; t < 2; ++t)
            #pragma unroll
            for (int j = 0; j < 4; ++j)
                accO[t][j] = __builtin_amdgcn_mfma_f32_16x16x32_bf16(
                    aw[t], bv[j], accO[t][j], 0, 0, 0);
        __builtin_amdgcn_s_setprio(0);
    }

    // ---- stage out tile into private LDS, then 16B coalesced stores ----
    #pragma unroll
    for (int t = 0; t < 2; ++t)
        #pragma unroll
        for (int j = 0; j < 4; ++j)
            #pragma unroll
            for (int r = 0; r < 4; ++r) {
                int row = t * 16 + quad * 4 + r;
                pw[row * 72 + j * 16 + l16] = f2bf(accO[t][j][r]);
            }

    u16* obase = ob + qrow * HS + h * 64;
    #pragma unroll
    for (int k = 0; k < 4; ++k) {
        int v   = k * 64 + lane;
        int row = v >> 3;
        int c8  = v & 7;
        *(uint4*)(obase + (long)row * HS + c8 * 8) =
            *(const uint4*)(&pw[row * 72 + c8 * 8]);
    }
}

// ---------------------------------------------------------------------------
extern "C" void kernel_launch(void* const* d_in, const int* in_sizes, int n_in,
                              void* d_out, int out_size, void* d_ws, size_t ws_size,
                              hipStream_t stream) {
    const float* query   = (const float*)d_in[0];  // [16,4096,512] fp32
    const float* context = (const float*)d_in[1];  // [16,77,768]   fp32
    const float* Wq      = (const float*)d_in[2];  // [512,512]     fp32
    const float* Wk      = (const float*)d_in[3];  // [768,512]     fp32
    const float* Wv      = (const float*)d_in[4];  // [768,512]     fp32
    const float* Wo      = (const float*)d_in[5];  // [512,512]     fp32
    const float* bo      = (const float*)d_in[6];  // [512]         fp32
    float* out = (float*)d_out;                    // [16,4096,512] fp32

    // workspace layout (u16 elements)
    u16* q_ws  = (u16*)d_ws;            // 16*4096*512 (also attn out, in-place)
    u16* kv_ws = q_ws + 33554432;       // 1232*1024
    u16* WqT   = kv_ws + 1261568;       // 512*512
    u16* WkvT  = WqT + 262144;          // 1024*768
    u16* WoT   = WkvT + 786432;         // 512*512
    u16* vt_ws = WkvT;                  // reuse (WkvT dead after kv-proj)

    // Wq transposed with the 1/sqrt(64) score scale folded in.
    transpose_one<<<(512 * 512 + 255) / 256, 256, 0, stream>>>(Wq, WqT, 512, 512, 0.125f);
    transpose_kv<<<(1024 * 768 + 255) / 256, 256, 0, stream>>>(Wk, Wv, WkvT);
    transpose_one<<<(512 * 512 + 255) / 256, 256, 0, stream>>>(Wo, WoT, 512, 512, 1.0f);

    // q projection: [65536,512](fp32) x [512,512] -> bf16 q_ws  (no-LDS direct)
    // 512 M-tiles x 2 N-tiles = 1024 wgs (div 8), ntl2 = 1
    gemm_direct<true, false><<<dim3(1024), 512, 0, stream>>>(
        (const void*)query, WqT, (void*)q_ws, nullptr, 65536, 512, 512, 1);
    // k,v projection fused: [1232,768](fp32) x [768,1024] -> bf16 ws (legacy)
    gemm_bt<true, false><<<dim3(40), 512, 0, stream>>>(
        (const void*)context, WkvT, (void*)kv_ws, nullptr, 1232, 768, 1024, 2);
    // V^T scatter (overwrites WkvT region, which is now dead)
    transpose_v<<<(16 * 8 * 64 * 96 + 255) / 256, 256, 0, stream>>>(kv_ws, vt_ws);
    // attention, in-place on q_ws (bf16), barrier-free main body
    attn_kernel<<<dim3(16, 8, 16), 512, 0, stream>>>(q_ws, kv_ws, vt_ws, q_ws);
    // output projection + fp32 bias: [65536,512](bf16) x [512,512] -> fp32 out
    // (no-LDS direct, bf16 A)
    gemm_direct<false, true><<<dim3(1024), 512, 0, stream>>>(
        q_ws, WoT, (void*)out, bo, 65536, 512, 512, 1);
}

// Round 9
// 377.972 us; speedup vs baseline: 1.5823x; 1.5823x over previous
//
#include <hip/hip_runtime.h>

typedef unsigned short u16;
typedef unsigned int u32;
typedef __bf16 bf16_t;
typedef bf16_t bf16x8 __attribute__((ext_vector_type(8)));
typedef float floatx4 __attribute__((ext_vector_type(4)));

__device__ __forceinline__ float bf2f(u16 h) {
    union { unsigned u; float f; } v;
    v.u = ((unsigned)h) << 16;
    return v.f;
}

__device__ __forceinline__ u16 f2bf(float f) {
    union { float f; unsigned u; } v;
    v.f = f;
    unsigned r = v.u + 0x7fffu + ((v.u >> 16) & 1u);
    return (u16)(r >> 16);
}

// async global->LDS, 16B per lane. LDS dest = uniform base + lane*16 (HW rule).
typedef __attribute__((address_space(1))) const u32 gu32;
typedef __attribute__((address_space(3))) u32 lu32;
__device__ __forceinline__ void gload16(const void* g, void* l) {
    __builtin_amdgcn_global_load_lds((gu32*)g, (lu32*)l, 16, 0, 0);
}

// ---------------------------------------------------------------------------
// Fused weight transposes (one dispatch): fp32 -> bf16 transposed.
//   [0, 262144)            WqT [512][512], scale 0.125 (attn score scale)
//   [262144, 1048576)      WkvT [1024][768] (rows 0..511 Wk^T, 512.. Wv^T)
//   [1048576, 1310720)     WoT [512][512]
// ---------------------------------------------------------------------------
__global__ void transpose_all(const float* __restrict__ Wq,
                              const float* __restrict__ Wk,
                              const float* __restrict__ Wv,
                              const float* __restrict__ Wo,
                              u16* __restrict__ WqT,
                              u16* __restrict__ WkvT,
                              u16* __restrict__ WoT) {
    int idx = blockIdx.x * 256 + threadIdx.x;
    if (idx < 262144) {
        int nrow = idx >> 9, k = idx & 511;
        WqT[idx] = f2bf(Wq[k * 512 + nrow] * 0.125f);
    } else if (idx < 1048576) {
        int i = idx - 262144;
        int nrow = i / 768, k = i - nrow * 768;
        WkvT[i] = f2bf((nrow < 512) ? Wk[k * 512 + nrow]
                                    : Wv[k * 512 + (nrow - 512)]);
    } else if (idx < 1310720) {
        int i = idx - 1048576;
        int nrow = i >> 9, k = i & 511;
        WoT[i] = f2bf(Wo[k * 512 + nrow]);
    }
}

// V^T for attention: vt[((n*8+h)*64+s)*96 + c] = v[n][c][h][s], zero c>=77.
__global__ void transpose_v(const u16* __restrict__ kv, u16* __restrict__ vt) {
    int idx = blockIdx.x * 256 + threadIdx.x;
    if (idx >= 16 * 8 * 64 * 96) return;
    int c  = idx % 96;
    int t1 = idx / 96;
    int s  = t1 & 63;
    int t2 = t1 >> 6;
    int h  = t2 & 7;
    int n  = t2 >> 3;
    u16 val = 0;
    if (c < 77) val = kv[((long)(n * 77 + c)) * 1024 + 512 + h * 64 + s];
    vt[idx] = val;
}

// ---------------------------------------------------------------------------
// GEMM body (round-4 proven): C[M,N] = A[M,K] * Bt[N,K]^T (+bias), bf16 MFMA.
// TM=128 x TN=256, 512 threads, counted-vmcnt double-buffered pipeline.
// Factored as a device function so one fused dispatch can run two GEMMs
// (different params) in disjoint blockIdx ranges.
// ---------------------------------------------------------------------------
#define TM 128
#define TN 256
#define TK 32

template <bool A_F32, bool OUT_F32>
__device__ __forceinline__ void gemm_body(
    char* smem, const void* __restrict__ A_, const u16* __restrict__ Bt,
    void* __restrict__ C_, const float* __restrict__ bias,
    int M, int K, int N, int ntl2, int wg, int nwg)
{
    constexpr int AB = A_F32 ? TM * TK * 4 : TM * TK * 2;
    constexpr int BB = TN * TK * 2;

    const int tid  = threadIdx.x;
    const int lane = tid & 63;
    const int wave = tid >> 6;
    const int quad = lane >> 4;
    const int l16  = lane & 15;
    const int wm   = (wave & 1) * 64;
    const int wn   = (wave >> 1) * 64;

    // XCD-aware bijective swizzle (nwg % 8 == 0), N-tile fastest within XCD.
    const int t   = (wg & 7) * (nwg >> 3) + (wg >> 3);
    const long bm = (long)(t >> ntl2) * TM;
    const long bn = (long)(t & ((1 << ntl2) - 1)) * TN;

    const float* Af = (const float*)A_;
    const u16*   Ab = (const u16*)A_;
    const long   Mm1 = (long)M - 1;

    floatx4 acc[4][4] = {};

    auto stage = [&](int b, int k0) {
        char* Abase = smem + b * (AB + BB);
        u16*  Bb    = (u16*)(Abase + AB);
        #pragma unroll
        for (int p = 0; p < 2; ++p) {
            int ch  = p * 512 + tid;
            int row = ch >> 2;
            int pc  = (ch & 3) ^ ((row >> 1) & 3);
            gload16(Bt + (bn + row) * K + k0 + pc * 8,
                    Bb + (p * 512 + wave * 64) * 8);
        }
        if (A_F32) {
            #pragma unroll
            for (int p = 0; p < 2; ++p) {
                int ch  = p * 512 + tid;
                int row = ch >> 3;
                int pcs = (ch & 7) ^ (row & 7);
                long gr = bm + row; if (gr > Mm1) gr = Mm1;
                gload16(Af + gr * K + k0 + pcs * 4,
                        (float*)Abase + (p * 512 + wave * 64) * 4);
            }
        } else {
            int row = tid >> 2;
            int pc  = (tid & 3) ^ ((row >> 1) & 3);
            long gr = bm + row; if (gr > Mm1) gr = Mm1;
            gload16(Ab + gr * K + k0 + pc * 8,
                    (u16*)Abase + (wave * 64) * 8);
        }
    };

    const int nk = K / TK;
    stage(0, 0);

    for (int tt = 0; tt < nk; ++tt) {
        const int cb = tt & 1;
        if (tt + 1 < nk) {
            stage(cb ^ 1, (tt + 1) * TK);
            if (A_F32) asm volatile("s_waitcnt vmcnt(4)" ::: "memory");
            else       asm volatile("s_waitcnt vmcnt(3)" ::: "memory");
        } else {
            asm volatile("s_waitcnt vmcnt(0)" ::: "memory");
        }
        __builtin_amdgcn_s_barrier();
        __builtin_amdgcn_sched_barrier(0);

        const char* Abase = smem + cb * (AB + BB);
        const u16*  Bb    = (const u16*)(Abase + AB);

        bf16x8 af[4], bfr[4];
        #pragma unroll
        for (int i = 0; i < 4; ++i) {
            int row = wm + i * 16 + l16;
            if (A_F32) {
                const char* arow = Abase + (size_t)row * 128;
                int x = row & 7;
                float4 f0 = *(const float4*)(arow + (((quad * 2)     ^ x) * 16));
                float4 f1 = *(const float4*)(arow + (((quad * 2 + 1) ^ x) * 16));
                union { bf16_t h[8]; bf16x8 v; } pk;
                pk.h[0] = (bf16_t)f0.x; pk.h[1] = (bf16_t)f0.y;
                pk.h[2] = (bf16_t)f0.z; pk.h[3] = (bf16_t)f0.w;
                pk.h[4] = (bf16_t)f1.x; pk.h[5] = (bf16_t)f1.y;
                pk.h[6] = (bf16_t)f1.z; pk.h[7] = (bf16_t)f1.w;
                af[i] = pk.v;
            } else {
                int pcs = quad ^ ((row >> 1) & 3);
                af[i] = *(const bf16x8*)((const u16*)Abase + row * 32 + pcs * 8);
            }
        }
        #pragma unroll
        for (int j = 0; j < 4; ++j) {
            int row = wn + j * 16 + l16;
            int pcs = quad ^ ((row >> 1) & 3);
            bfr[j] = *(const bf16x8*)(Bb + row * 32 + pcs * 8);
        }
        #pragma unroll
        for (int i = 0; i < 4; ++i)
            #pragma unroll
            for (int j = 0; j < 4; ++j)
                acc[i][j] = __builtin_amdgcn_mfma_f32_16x16x32_bf16(
                    af[i], bfr[j], acc[i][j], 0, 0, 0);

        __builtin_amdgcn_s_barrier();
    }

    #pragma unroll
    for (int i = 0; i < 4; ++i) {
        #pragma unroll
        for (int r = 0; r < 4; ++r) {
            long row = bm + wm + i * 16 + quad * 4 + r;
            if (row >= M) continue;
            #pragma unroll
            for (int j = 0; j < 4; ++j) {
                long col = bn + wn + j * 16 + l16;
                float val = acc[i][j][r];
                if (bias) val += bias[col];
                if (OUT_F32) ((float*)C_)[row * N + col] = val;
                else         ((u16*)C_)[row * N + col] = f2bf(val);
            }
        }
    }
}

// Fused projection dispatch: blocks [0,80) run the kv projection
// ([1232,768] x [768,1024]), blocks [80,1104) run the q projection
// ([65536,512] x [512,512]). kv blocks first so they start immediately and
// their latency-exposed 24-step chain hides under q-proj's execution
// (separately, kv-proj left 216/256 CUs idle for its whole duration).
// Wave-uniform branch; both branches use identical 64 KB LDS.
__global__ __launch_bounds__(512, 4) void proj_fused(
    const float* __restrict__ query,   const u16* __restrict__ WqT,
    u16* __restrict__ q_ws,
    const float* __restrict__ context, const u16* __restrict__ WkvT,
    u16* __restrict__ kv_ws)
{
    __shared__ __align__(16) char smem[2 * (TM * TK * 4 + TN * TK * 2)];
    if (blockIdx.x < 80)
        gemm_body<true, false>(smem, context, WkvT, kv_ws, nullptr,
                               1232, 768, 1024, 2, blockIdx.x, 80);
    else
        gemm_body<true, false>(smem, query, WqT, q_ws, nullptr,
                               65536, 512, 512, 1, blockIdx.x - 80, 1024);
}

// ---------------------------------------------------------------------------
// gemm256 (round-5/6 verified for bf16-A): BM=BN=256, BK=64, 512 threads =
// 8 waves (2M x 4N), per-wave out 128x64. Used for the o-proj.
// ---------------------------------------------------------------------------
template <bool OUT_F32>
__global__ __launch_bounds__(512, 2) void gemm256(
    const u16* __restrict__ A, const u16* __restrict__ Bt,
    void* __restrict__ C_, const float* __restrict__ bias,
    int M, int K, int N, int ntl2)
{
    __shared__ u16 As[2][256 * 64];
    __shared__ u16 Bs[2][256 * 64];

    const int tid  = threadIdx.x;
    const int lane = tid & 63;
    const int wave = tid >> 6;      // 0..7
    const int quad = lane >> 4;
    const int l16  = lane & 15;
    const int wr   = wave & 1;      // M half (128 rows)
    const int wc   = wave >> 1;     // N quarter (64 cols)

    const int nwg = gridDim.x;
    const int wg  = blockIdx.x;
    const int t   = (wg & 7) * (nwg >> 3) + (wg >> 3);
    const long bm = (long)(t >> ntl2) * 256;
    const long bn = (long)(t & ((1 << ntl2) - 1)) * 256;

    floatx4 acc[8][4] = {};

    auto stage = [&](int b, int k0) {
        #pragma unroll
        for (int p = 0; p < 4; ++p) {
            int ch = p * 512 + tid;
            int r  = ch >> 3;
            int cs = (ch & 7) ^ (r & 7);
            gload16(A + (bm + r) * K + k0 + cs * 8,
                    &As[b][(p * 512 + wave * 64) * 8]);
        }
        #pragma unroll
        for (int p = 0; p < 4; ++p) {
            int ch = p * 512 + tid;
            int r  = ch >> 3;
            int cs = (ch & 7) ^ (r & 7);
            gload16(Bt + (bn + r) * K + k0 + cs * 8,
                    &Bs[b][(p * 512 + wave * 64) * 8]);
        }
    };

    const int nk = K >> 6;    // BK=64
    stage(0, 0);
    asm volatile("s_waitcnt vmcnt(0)" ::: "memory");
    __builtin_amdgcn_s_barrier();

    for (int tt = 0; tt < nk; ++tt) {
        const int cb = tt & 1;
        const u16* Ab = As[cb];
        const u16* Bb = Bs[cb];

        bf16x8 bfr[4][2];   // B frags held across all 4 phases

        #pragma unroll
        for (int p = 0; p < 4; ++p) {
            bf16x8 af[2][2];
            #pragma unroll
            for (int ii = 0; ii < 2; ++ii) {
                int row = wr * 128 + (p * 2 + ii) * 16 + l16;
                #pragma unroll
                for (int kk = 0; kk < 2; ++kk)
                    af[ii][kk] = *(const bf16x8*)(
                        Ab + row * 64 + (((kk * 4) + quad) ^ (row & 7)) * 8);
            }
            if (p == 0) {
                #pragma unroll
                for (int j = 0; j < 4; ++j) {
                    int row = wc * 64 + j * 16 + l16;
                    #pragma unroll
                    for (int kk = 0; kk < 2; ++kk)
                        bfr[j][kk] = *(const bf16x8*)(
                            Bb + row * 64 + (((kk * 4) + quad) ^ (row & 7)) * 8);
                }
                if (tt + 1 < nk) stage(cb ^ 1, (tt + 1) << 6);
            }
            asm volatile("s_waitcnt lgkmcnt(0)" ::: "memory");
            __builtin_amdgcn_sched_barrier(0);
            __builtin_amdgcn_s_setprio(1);
            #pragma unroll
            for (int ii = 0; ii < 2; ++ii)
                #pragma unroll
                for (int j = 0; j < 4; ++j)
                    #pragma unroll
                    for (int kk = 0; kk < 2; ++kk)
                        acc[p * 2 + ii][j] = __builtin_amdgcn_mfma_f32_16x16x32_bf16(
                            af[ii][kk], bfr[j][kk], acc[p * 2 + ii][j], 0, 0, 0);
            __builtin_amdgcn_s_setprio(0);
            if (p == 3)
                asm volatile("s_waitcnt vmcnt(0)" ::: "memory");
            __builtin_amdgcn_s_barrier();
        }
    }

    float bj[4];
    #pragma unroll
    for (int j = 0; j < 4; ++j)
        bj[j] = bias ? bias[bn + wc * 64 + j * 16 + l16] : 0.f;

    #pragma unroll
    for (int i = 0; i < 8; ++i) {
        #pragma unroll
        for (int r = 0; r < 4; ++r) {
            long row = bm + wr * 128 + i * 16 + quad * 4 + r;
            #pragma unroll
            for (int j = 0; j < 4; ++j) {
                long col = bn + wc * 64 + j * 16 + l16;
                float val = acc[i][j][r] + bj[j];
                if (OUT_F32) ((float*)C_)[row * N + col] = val;
                else         ((u16*)C_)[row * N + col] = f2bf(val);
            }
        }
    }
}

// ---------------------------------------------------------------------------
// Fused attention v5 (round-7 proven). Barrier-free main body, coalesced
// 16B output stores via per-wave LDS scratch, setprio around MFMA clusters.
// ---------------------------------------------------------------------------
__global__ __launch_bounds__(512, 4) void attn_kernel(
    const u16* __restrict__ qb,   // [N, 4096, 512] bf16 (scores pre-scaled)
    const u16* __restrict__ kvb,  // [N*77, 1024] bf16 (cols 0..511 k)
    const u16* __restrict__ vt,   // [(n*8+h)*64+s][96] bf16, zero c>=77
    u16* __restrict__ ob)         // [N, 4096, 512] bf16
{
    const int QL = 4096, HS = 512;
    const int q0 = blockIdx.x * 256;
    const int h  = blockIdx.y;
    const int n  = blockIdx.z;

    __shared__ u16 ks [80 * 72];        // K [c][s], c zero-padded to 80
    __shared__ u16 vts[64 * 104];       // V^T [s][c], cols zero-padded to 96
    __shared__ u16 pS [8][32 * 104];    // per-wave P / output scratch

    const int tid  = threadIdx.x;
    const int lane = tid & 63;
    const int wave = tid >> 6;          // 0..7
    const int quad = lane >> 4;
    const int l16  = lane & 15;

    // ---- issue Q fragment loads first (hide under K/V staging) ----
    const long qrow = (long)n * QL + q0 + wave * 32;
    bf16x8 aq[2][2];
    #pragma unroll
    for (int t = 0; t < 2; ++t)
        #pragma unroll
        for (int kk = 0; kk < 2; ++kk)
            aq[t][kk] = *(const bf16x8*)(
                qb + (qrow + t * 16 + l16) * HS + h * 64 + kk * 32 + quad * 8);

    // ---- stage K rows (coalesced, zero-pad c>=77) ----
    const u16* kbase = kvb + (long)n * 77 * 1024 + h * 64;
    for (int v = tid; v < 640; v += 512) {
        int c = v >> 3, g = (v & 7) * 8;
        uint4 val = make_uint4(0, 0, 0, 0);
        if (c < 77) val = *(const uint4*)(kbase + (long)c * 1024 + g);
        *(uint4*)(&ks[c * 72 + g]) = val;
    }
    // ---- stage V^T rows from vt_ws ----
    const u16* vtbase = vt + (long)((n * 8 + h) * 64) * 96;
    for (int v = tid; v < 768; v += 512) {           // 64 rows x 12 uint4
        int r = v / 12, c8 = v - r * 12;
        *(uint4*)(&vts[r * 104 + c8 * 8]) = *(const uint4*)(vtbase + v * 8);
    }
    __syncthreads();    // the ONLY block-wide barrier

    // ---- QK^T: wave's 32 rows x 80 cols (2 row-tiles x 5 col-tiles) ----
    floatx4 accS[2][5] = {};
    #pragma unroll
    for (int kk = 0; kk < 2; ++kk) {
        bf16x8 bk[5];
        #pragma unroll
        for (int j = 0; j < 5; ++j)
            bk[j] = *(const bf16x8*)(&ks[(j * 16 + l16) * 72 + kk * 32 + quad * 8]);
        __builtin_amdgcn_s_setprio(1);
        #pragma unroll
        for (int t = 0; t < 2; ++t)
            #pragma unroll
            for (int j = 0; j < 5; ++j)
                accS[t][j] = __builtin_amdgcn_mfma_f32_16x16x32_bf16(
                    aq[t][kk], bk[j], accS[t][j], 0, 0, 0);
        __builtin_amdgcn_s_setprio(0);
    }

    // ---- softmax in registers; write P rows into private LDS ----
    const bool v4ok = (l16 < 13);       // col 64+l16 valid iff < 77
    u16* pw = pS[wave];
    #pragma unroll
    for (int t = 0; t < 2; ++t) {
        #pragma unroll
        for (int r = 0; r < 4; ++r) {
            float v0 = accS[t][0][r];
            float v1 = accS[t][1][r];
            float v2 = accS[t][2][r];
            float v3 = accS[t][3][r];
            float v4 = v4ok ? accS[t][4][r] : -1e30f;
            float mx = fmaxf(fmaxf(fmaxf(v0, v1), fmaxf(v2, v3)), v4);
            mx = fmaxf(mx, __shfl_xor(mx, 1));
            mx = fmaxf(mx, __shfl_xor(mx, 2));
            mx = fmaxf(mx, __shfl_xor(mx, 4));
            mx = fmaxf(mx, __shfl_xor(mx, 8));
            float e0 = __expf(v0 - mx), e1 = __expf(v1 - mx);
            float e2 = __expf(v2 - mx), e3 = __expf(v3 - mx);
            float e4 = __expf(v4 - mx);
            float sum = e0 + e1 + e2 + e3 + e4;
            sum += __shfl_xor(sum, 1);
            sum += __shfl_xor(sum, 2);
            sum += __shfl_xor(sum, 4);
            sum += __shfl_xor(sum, 8);
            float inv = 1.f / sum;
            int row = t * 16 + quad * 4 + r;
            pw[row * 104 +  0 + l16] = f2bf(e0 * inv);
            pw[row * 104 + 16 + l16] = f2bf(e1 * inv);
            pw[row * 104 + 32 + l16] = f2bf(e2 * inv);
            pw[row * 104 + 48 + l16] = f2bf(e3 * inv);
            pw[row * 104 + 64 + l16] = f2bf(e4 * inv);
            pw[row * 104 + 80 + l16] = 0;
        }
    }
    // (same-wave ds_write -> ds_read ordered by lgkmcnt; LDS ops are in-order)

    // ---- PV: out[32,64] = P[32,96] @ V[96,64] ----
    floatx4 accO[2][4] = {};
    #pragma unroll
    for (int kk = 0; kk < 3; ++kk) {
        bf16x8 aw[2], bv[4];
        #pragma unroll
        for (int t = 0; t < 2; ++t)
            aw[t] = *(const bf16x8*)(&pw[(t * 16 + l16) * 104 + kk * 32 + quad * 8]);
        #pragma unroll
        for (int j = 0; j < 4; ++j)
            bv[j] = *(const bf16x8*)(&vts[(j * 16 + l16) * 104 + kk * 32 + quad * 8]);
        __builtin_amdgcn_s_setprio(1);
        #pragma unroll
        for (int t = 0; t < 2; ++t)
            #pragma unroll
            for (int j = 0; j < 4; ++j)
                accO[t][j] = __builtin_amdgcn_mfma_f32_16x16x32_bf16(
                    aw[t], bv[j], accO[t][j], 0, 0, 0);
        __builtin_amdgcn_s_setprio(0);
    }

    // ---- stage out tile into private LDS, then 16B coalesced stores ----
    #pragma unroll
    for (int t = 0; t < 2; ++t)
        #pragma unroll
        for (int j = 0; j < 4; ++j)
            #pragma unroll
            for (int r = 0; r < 4; ++r) {
                int row = t * 16 + quad * 4 + r;
                pw[row * 72 + j * 16 + l16] = f2bf(accO[t][j][r]);
            }

    u16* obase = ob + qrow * HS + h * 64;
    #pragma unroll
    for (int k = 0; k < 4; ++k) {
        int v   = k * 64 + lane;
        int row = v >> 3;
        int c8  = v & 7;
        *(uint4*)(obase + (long)row * HS + c8 * 8) =
            *(const uint4*)(&pw[row * 72 + c8 * 8]);
    }
}

// ---------------------------------------------------------------------------
extern "C" void kernel_launch(void* const* d_in, const int* in_sizes, int n_in,
                              void* d_out, int out_size, void* d_ws, size_t ws_size,
                              hipStream_t stream) {
    const float* query   = (const float*)d_in[0];  // [16,4096,512] fp32
    const float* context = (const float*)d_in[1];  // [16,77,768]   fp32
    const float* Wq      = (const float*)d_in[2];  // [512,512]     fp32
    const float* Wk      = (const float*)d_in[3];  // [768,512]     fp32
    const float* Wv      = (const float*)d_in[4];  // [768,512]     fp32
    const float* Wo      = (const float*)d_in[5];  // [512,512]     fp32
    const float* bo      = (const float*)d_in[6];  // [512]         fp32
    float* out = (float*)d_out;                    // [16,4096,512] fp32

    // workspace layout (u16 elements)
    u16* q_ws  = (u16*)d_ws;            // 16*4096*512 (also attn out, in-place)
    u16* kv_ws = q_ws + 33554432;       // 1232*1024
    u16* WqT   = kv_ws + 1261568;       // 512*512
    u16* WkvT  = WqT + 262144;          // 1024*768
    u16* WoT   = WkvT + 786432;         // 512*512
    u16* vt_ws = WkvT;                  // reuse (WkvT dead after proj_fused)

    // one dispatch for all three weight transposes (Wq pre-scaled by 0.125)
    transpose_all<<<dim3(5120), 256, 0, stream>>>(Wq, Wk, Wv, Wo, WqT, WkvT, WoT);

    // q projection + kv projection fused in one grid: blocks [0,80) = kv
    // ([1232,768]x[768,1024] -> kv_ws), blocks [80,1104) = q
    // ([65536,512]x[512,512] -> q_ws). kv's 40-block-equivalent idle time
    // now overlaps q-proj's execution.
    proj_fused<<<dim3(1104), 512, 0, stream>>>(
        query, WqT, q_ws, context, WkvT, kv_ws);

    // V^T scatter (overwrites WkvT region, which is now dead)
    transpose_v<<<(16 * 8 * 64 * 96 + 255) / 256, 256, 0, stream>>>(kv_ws, vt_ws);
    // attention, in-place on q_ws (bf16), barrier-free main body
    attn_kernel<<<dim3(16, 8, 16), 512, 0, stream>>>(q_ws, kv_ws, vt_ws, q_ws);
    // output projection + fp32 bias: [65536,512](bf16) x [512,512] -> fp32 out
    gemm256<true><<<dim3(512), 512, 0, stream>>>(
        q_ws, WoT, (void*)out, bo, 65536, 512, 512, 1);
}

// Round 10
// 375.481 us; speedup vs baseline: 1.5928x; 1.0066x over previous
//
#include <hip/hip_runtime.h>

typedef unsigned short u16;
typedef unsigned int u32;
typedef __bf16 bf16_t;
typedef bf16_t bf16x8 __attribute__((ext_vector_type(8)));
typedef float floatx4 __attribute__((ext_vector_type(4)));

__device__ __forceinline__ float bf2f(u16 h) {
    union { unsigned u; float f; } v;
    v.u = ((unsigned)h) << 16;
    return v.f;
}

__device__ __forceinline__ u16 f2bf(float f) {
    union { float f; unsigned u; } v;
    v.f = f;
    unsigned r = v.u + 0x7fffu + ((v.u >> 16) & 1u);
    return (u16)(r >> 16);
}

// async global->LDS, 16B per lane. LDS dest = uniform base + lane*16 (HW rule).
typedef __attribute__((address_space(1))) const u32 gu32;
typedef __attribute__((address_space(3))) u32 lu32;
__device__ __forceinline__ void gload16(const void* g, void* l) {
    __builtin_amdgcn_global_load_lds((gu32*)g, (lu32*)l, 16, 0, 0);
}

// ---------------------------------------------------------------------------
// Fused weight transposes + vt zero-init (one dispatch):
//   [0, 262144)            WqT [512][512], scale 0.125 (attn score scale)
//   [262144, 1048576)      WkvT [1024][768] (rows 0..511 Wk^T, 512.. Wv^T)
//   [1048576, 1310720)     WoT [512][512]
//   [1310720, 2097152)     vt zero-fill (c>=77 padding; c<77 overwritten by
//                          the kv-proj epilogue scatter)
// ---------------------------------------------------------------------------
__global__ void transpose_all(const float* __restrict__ Wq,
                              const float* __restrict__ Wk,
                              const float* __restrict__ Wv,
                              const float* __restrict__ Wo,
                              u16* __restrict__ WqT,
                              u16* __restrict__ WkvT,
                              u16* __restrict__ WoT,
                              u16* __restrict__ vt) {
    int idx = blockIdx.x * 256 + threadIdx.x;
    if (idx < 262144) {
        int nrow = idx >> 9, k = idx & 511;
        WqT[idx] = f2bf(Wq[k * 512 + nrow] * 0.125f);
    } else if (idx < 1048576) {
        int i = idx - 262144;
        int nrow = i / 768, k = i - nrow * 768;
        WkvT[i] = f2bf((nrow < 512) ? Wk[k * 512 + nrow]
                                    : Wv[k * 512 + (nrow - 512)]);
    } else if (idx < 1310720) {
        int i = idx - 1048576;
        int nrow = i >> 9, k = i & 511;
        WoT[i] = f2bf(Wo[k * 512 + nrow]);
    } else if (idx < 2097152) {
        vt[idx - 1310720] = 0;
    }
}

// ---------------------------------------------------------------------------
// GEMM body (round-4 proven): C[M,N] = A[M,K] * Bt[N,K]^T, bf16 MFMA.
// TM=128 x TN=256, 512 threads, counted-vmcnt double-buffered pipeline.
// VT_SCATTER: for the kv projection, cols >= 512 are the V-half; scatter
// them directly into the attention's V^T layout
//   vt[((n*8+h)*64+s)*96 + c], n=row/77, c=row%77, h=(col-512)>>6, s=(col-512)&63
// (replaces the separate transpose_v dispatch; ~15us launch overhead saved).
// ---------------------------------------------------------------------------
#define TM 128
#define TN 256
#define TK 32

template <bool A_F32, bool OUT_F32, bool VT_SCATTER>
__device__ __forceinline__ void gemm_body(
    char* smem, const void* __restrict__ A_, const u16* __restrict__ Bt,
    void* __restrict__ C_, const float* __restrict__ bias,
    u16* __restrict__ vt,
    int M, int K, int N, int ntl2, int wg, int nwg)
{
    constexpr int AB = A_F32 ? TM * TK * 4 : TM * TK * 2;
    constexpr int BB = TN * TK * 2;

    const int tid  = threadIdx.x;
    const int lane = tid & 63;
    const int wave = tid >> 6;
    const int quad = lane >> 4;
    const int l16  = lane & 15;
    const int wm   = (wave & 1) * 64;
    const int wn   = (wave >> 1) * 64;

    // XCD-aware bijective swizzle (nwg % 8 == 0), N-tile fastest within XCD.
    const int t   = (wg & 7) * (nwg >> 3) + (wg >> 3);
    const long bm = (long)(t >> ntl2) * TM;
    const long bn = (long)(t & ((1 << ntl2) - 1)) * TN;

    const float* Af = (const float*)A_;
    const u16*   Ab = (const u16*)A_;
    const long   Mm1 = (long)M - 1;

    floatx4 acc[4][4] = {};

    auto stage = [&](int b, int k0) {
        char* Abase = smem + b * (AB + BB);
        u16*  Bb    = (u16*)(Abase + AB);
        #pragma unroll
        for (int p = 0; p < 2; ++p) {
            int ch  = p * 512 + tid;
            int row = ch >> 2;
            int pc  = (ch & 3) ^ ((row >> 1) & 3);
            gload16(Bt + (bn + row) * K + k0 + pc * 8,
                    Bb + (p * 512 + wave * 64) * 8);
        }
        if (A_F32) {
            #pragma unroll
            for (int p = 0; p < 2; ++p) {
                int ch  = p * 512 + tid;
                int row = ch >> 3;
                int pcs = (ch & 7) ^ (row & 7);
                long gr = bm + row; if (gr > Mm1) gr = Mm1;
                gload16(Af + gr * K + k0 + pcs * 4,
                        (float*)Abase + (p * 512 + wave * 64) * 4);
            }
        } else {
            int row = tid >> 2;
            int pc  = (tid & 3) ^ ((row >> 1) & 3);
            long gr = bm + row; if (gr > Mm1) gr = Mm1;
            gload16(Ab + gr * K + k0 + pc * 8,
                    (u16*)Abase + (wave * 64) * 8);
        }
    };

    const int nk = K / TK;
    stage(0, 0);

    for (int tt = 0; tt < nk; ++tt) {
        const int cb = tt & 1;
        if (tt + 1 < nk) {
            stage(cb ^ 1, (tt + 1) * TK);
            if (A_F32) asm volatile("s_waitcnt vmcnt(4)" ::: "memory");
            else       asm volatile("s_waitcnt vmcnt(3)" ::: "memory");
        } else {
            asm volatile("s_waitcnt vmcnt(0)" ::: "memory");
        }
        __builtin_amdgcn_s_barrier();
        __builtin_amdgcn_sched_barrier(0);

        const char* Abase = smem + cb * (AB + BB);
        const u16*  Bb    = (const u16*)(Abase + AB);

        bf16x8 af[4], bfr[4];
        #pragma unroll
        for (int i = 0; i < 4; ++i) {
            int row = wm + i * 16 + l16;
            if (A_F32) {
                const char* arow = Abase + (size_t)row * 128;
                int x = row & 7;
                float4 f0 = *(const float4*)(arow + (((quad * 2)     ^ x) * 16));
                float4 f1 = *(const float4*)(arow + (((quad * 2 + 1) ^ x) * 16));
                union { bf16_t h[8]; bf16x8 v; } pk;
                pk.h[0] = (bf16_t)f0.x; pk.h[1] = (bf16_t)f0.y;
                pk.h[2] = (bf16_t)f0.z; pk.h[3] = (bf16_t)f0.w;
                pk.h[4] = (bf16_t)f1.x; pk.h[5] = (bf16_t)f1.y;
                pk.h[6] = (bf16_t)f1.z; pk.h[7] = (bf16_t)f1.w;
                af[i] = pk.v;
            } else {
                int pcs = quad ^ ((row >> 1) & 3);
                af[i] = *(const bf16x8*)((const u16*)Abase + row * 32 + pcs * 8);
            }
        }
        #pragma unroll
        for (int j = 0; j < 4; ++j) {
            int row = wn + j * 16 + l16;
            int pcs = quad ^ ((row >> 1) & 3);
            bfr[j] = *(const bf16x8*)(Bb + row * 32 + pcs * 8);
        }
        #pragma unroll
        for (int i = 0; i < 4; ++i)
            #pragma unroll
            for (int j = 0; j < 4; ++j)
                acc[i][j] = __builtin_amdgcn_mfma_f32_16x16x32_bf16(
                    af[i], bfr[j], acc[i][j], 0, 0, 0);

        __builtin_amdgcn_s_barrier();
    }

    #pragma unroll
    for (int i = 0; i < 4; ++i) {
        #pragma unroll
        for (int r = 0; r < 4; ++r) {
            long row = bm + wm + i * 16 + quad * 4 + r;
            if (row >= M) continue;
            #pragma unroll
            for (int j = 0; j < 4; ++j) {
                long col = bn + wn + j * 16 + l16;
                float val = acc[i][j][r];
                if (bias) val += bias[col];
                if (VT_SCATTER && col >= 512) {
                    // V-half -> V^T layout for attention
                    int n_ = (int)(row / 77);
                    int c_ = (int)(row - (long)n_ * 77);
                    int hs = (int)col - 512;
                    vt[((long)(n_ * 8 + (hs >> 6)) * 64 + (hs & 63)) * 96 + c_]
                        = f2bf(val);
                } else if (OUT_F32) {
                    ((float*)C_)[row * N + col] = val;
                } else {
                    ((u16*)C_)[row * N + col] = f2bf(val);
                }
            }
        }
    }
}

// Fused projection dispatch: blocks [0,80) run the kv projection
// ([1232,768] x [768,1024]; K-half -> kv_ws, V-half scattered to vt),
// blocks [80,1104) run the q projection ([65536,512] x [512,512] -> q_ws).
// kv blocks first so their latency-exposed chain hides under q-proj.
__global__ __launch_bounds__(512, 4) void proj_fused(
    const float* __restrict__ query,   const u16* __restrict__ WqT,
    u16* __restrict__ q_ws,
    const float* __restrict__ context, const u16* __restrict__ WkvT,
    u16* __restrict__ kv_ws,           u16* __restrict__ vt)
{
    __shared__ __align__(16) char smem[2 * (TM * TK * 4 + TN * TK * 2)];
    if (blockIdx.x < 80)
        gemm_body<true, false, true>(smem, context, WkvT, kv_ws, nullptr, vt,
                                     1232, 768, 1024, 2, blockIdx.x, 80);
    else
        gemm_body<true, false, false>(smem, query, WqT, q_ws, nullptr, nullptr,
                                      65536, 512, 512, 1, blockIdx.x - 80, 1024);
}

// ---------------------------------------------------------------------------
// gemm256 (round-5/6 verified for bf16-A): BM=BN=256, BK=64, 512 threads =
// 8 waves (2M x 4N), per-wave out 128x64. Used for the o-proj.
// ---------------------------------------------------------------------------
template <bool OUT_F32>
__global__ __launch_bounds__(512, 2) void gemm256(
    const u16* __restrict__ A, const u16* __restrict__ Bt,
    void* __restrict__ C_, const float* __restrict__ bias,
    int M, int K, int N, int ntl2)
{
    __shared__ u16 As[2][256 * 64];
    __shared__ u16 Bs[2][256 * 64];

    const int tid  = threadIdx.x;
    const int lane = tid & 63;
    const int wave = tid >> 6;      // 0..7
    const int quad = lane >> 4;
    const int l16  = lane & 15;
    const int wr   = wave & 1;      // M half (128 rows)
    const int wc   = wave >> 1;     // N quarter (64 cols)

    const int nwg = gridDim.x;
    const int wg  = blockIdx.x;
    const int t   = (wg & 7) * (nwg >> 3) + (wg >> 3);
    const long bm = (long)(t >> ntl2) * 256;
    const long bn = (long)(t & ((1 << ntl2) - 1)) * 256;

    floatx4 acc[8][4] = {};

    auto stage = [&](int b, int k0) {
        #pragma unroll
        for (int p = 0; p < 4; ++p) {
            int ch = p * 512 + tid;
            int r  = ch >> 3;
            int cs = (ch & 7) ^ (r & 7);
            gload16(A + (bm + r) * K + k0 + cs * 8,
                    &As[b][(p * 512 + wave * 64) * 8]);
        }
        #pragma unroll
        for (int p = 0; p < 4; ++p) {
            int ch = p * 512 + tid;
            int r  = ch >> 3;
            int cs = (ch & 7) ^ (r & 7);
            gload16(Bt + (bn + r) * K + k0 + cs * 8,
                    &Bs[b][(p * 512 + wave * 64) * 8]);
        }
    };

    const int nk = K >> 6;    // BK=64
    stage(0, 0);
    asm volatile("s_waitcnt vmcnt(0)" ::: "memory");
    __builtin_amdgcn_s_barrier();

    for (int tt = 0; tt < nk; ++tt) {
        const int cb = tt & 1;
        const u16* Ab = As[cb];
        const u16* Bb = Bs[cb];

        bf16x8 bfr[4][2];   // B frags held across all 4 phases

        #pragma unroll
        for (int p = 0; p < 4; ++p) {
            bf16x8 af[2][2];
            #pragma unroll
            for (int ii = 0; ii < 2; ++ii) {
                int row = wr * 128 + (p * 2 + ii) * 16 + l16;
                #pragma unroll
                for (int kk = 0; kk < 2; ++kk)
                    af[ii][kk] = *(const bf16x8*)(
                        Ab + row * 64 + (((kk * 4) + quad) ^ (row & 7)) * 8);
            }
            if (p == 0) {
                #pragma unroll
                for (int j = 0; j < 4; ++j) {
                    int row = wc * 64 + j * 16 + l16;
                    #pragma unroll
                    for (int kk = 0; kk < 2; ++kk)
                        bfr[j][kk] = *(const bf16x8*)(
                            Bb + row * 64 + (((kk * 4) + quad) ^ (row & 7)) * 8);
                }
                if (tt + 1 < nk) stage(cb ^ 1, (tt + 1) << 6);
            }
            asm volatile("s_waitcnt lgkmcnt(0)" ::: "memory");
            __builtin_amdgcn_sched_barrier(0);
            __builtin_amdgcn_s_setprio(1);
            #pragma unroll
            for (int ii = 0; ii < 2; ++ii)
                #pragma unroll
                for (int j = 0; j < 4; ++j)
                    #pragma unroll
                    for (int kk = 0; kk < 2; ++kk)
                        acc[p * 2 + ii][j] = __builtin_amdgcn_mfma_f32_16x16x32_bf16(
                            af[ii][kk], bfr[j][kk], acc[p * 2 + ii][j], 0, 0, 0);
            __builtin_amdgcn_s_setprio(0);
            if (p == 3)
                asm volatile("s_waitcnt vmcnt(0)" ::: "memory");
            __builtin_amdgcn_s_barrier();
        }
    }

    float bj[4];
    #pragma unroll
    for (int j = 0; j < 4; ++j)
        bj[j] = bias ? bias[bn + wc * 64 + j * 16 + l16] : 0.f;

    #pragma unroll
    for (int i = 0; i < 8; ++i) {
        #pragma unroll
        for (int r = 0; r < 4; ++r) {
            long row = bm + wr * 128 + i * 16 + quad * 4 + r;
            #pragma unroll
            for (int j = 0; j < 4; ++j) {
                long col = bn + wc * 64 + j * 16 + l16;
                float val = acc[i][j][r] + bj[j];
                if (OUT_F32) ((float*)C_)[row * N + col] = val;
                else         ((u16*)C_)[row * N + col] = f2bf(val);
            }
        }
    }
}

// ---------------------------------------------------------------------------
// Fused attention v5 (round-7 proven). Barrier-free main body, coalesced
// 16B output stores via per-wave LDS scratch, setprio around MFMA clusters.
// ---------------------------------------------------------------------------
__global__ __launch_bounds__(512, 4) void attn_kernel(
    const u16* __restrict__ qb,   // [N, 4096, 512] bf16 (scores pre-scaled)
    const u16* __restrict__ kvb,  // [N*77, 1024] bf16 (cols 0..511 k)
    const u16* __restrict__ vt,   // [(n*8+h)*64+s][96] bf16, zero c>=77
    u16* __restrict__ ob)         // [N, 4096, 512] bf16
{
    const int QL = 4096, HS = 512;
    const int q0 = blockIdx.x * 256;
    const int h  = blockIdx.y;
    const int n  = blockIdx.z;

    __shared__ u16 ks [80 * 72];        // K [c][s], c zero-padded to 80
    __shared__ u16 vts[64 * 104];       // V^T [s][c], cols zero-padded to 96
    __shared__ u16 pS [8][32 * 104];    // per-wave P / output scratch

    const int tid  = threadIdx.x;
    const int lane = tid & 63;
    const int wave = tid >> 6;          // 0..7
    const int quad = lane >> 4;
    const int l16  = lane & 15;

    // ---- issue Q fragment loads first (hide under K/V staging) ----
    const long qrow = (long)n * QL + q0 + wave * 32;
    bf16x8 aq[2][2];
    #pragma unroll
    for (int t = 0; t < 2; ++t)
        #pragma unroll
        for (int kk = 0; kk < 2; ++kk)
            aq[t][kk] = *(const bf16x8*)(
                qb + (qrow + t * 16 + l16) * HS + h * 64 + kk * 32 + quad * 8);

    // ---- stage K rows (coalesced, zero-pad c>=77) ----
    const u16* kbase = kvb + (long)n * 77 * 1024 + h * 64;
    for (int v = tid; v < 640; v += 512) {
        int c = v >> 3, g = (v & 7) * 8;
        uint4 val = make_uint4(0, 0, 0, 0);
        if (c < 77) val = *(const uint4*)(kbase + (long)c * 1024 + g);
        *(uint4*)(&ks[c * 72 + g]) = val;
    }
    // ---- stage V^T rows from vt scratch ----
    const u16* vtbase = vt + (long)((n * 8 + h) * 64) * 96;
    for (int v = tid; v < 768; v += 512) {           // 64 rows x 12 uint4
        int r = v / 12, c8 = v - r * 12;
        *(uint4*)(&vts[r * 104 + c8 * 8]) = *(const uint4*)(vtbase + v * 8);
    }
    __syncthreads();    // the ONLY block-wide barrier

    // ---- QK^T: wave's 32 rows x 80 cols (2 row-tiles x 5 col-tiles) ----
    floatx4 accS[2][5] = {};
    #pragma unroll
    for (int kk = 0; kk < 2; ++kk) {
        bf16x8 bk[5];
        #pragma unroll
        for (int j = 0; j < 5; ++j)
            bk[j] = *(const bf16x8*)(&ks[(j * 16 + l16) * 72 + kk * 32 + quad * 8]);
        __builtin_amdgcn_s_setprio(1);
        #pragma unroll
        for (int t = 0; t < 2; ++t)
            #pragma unroll
            for (int j = 0; j < 5; ++j)
                accS[t][j] = __builtin_amdgcn_mfma_f32_16x16x32_bf16(
                    aq[t][kk], bk[j], accS[t][j], 0, 0, 0);
        __builtin_amdgcn_s_setprio(0);
    }

    // ---- softmax in registers; write P rows into private LDS ----
    const bool v4ok = (l16 < 13);       // col 64+l16 valid iff < 77
    u16* pw = pS[wave];
    #pragma unroll
    for (int t = 0; t < 2; ++t) {
        #pragma unroll
        for (int r = 0; r < 4; ++r) {
            float v0 = accS[t][0][r];
            float v1 = accS[t][1][r];
            float v2 = accS[t][2][r];
            float v3 = accS[t][3][r];
            float v4 = v4ok ? accS[t][4][r] : -1e30f;
            float mx = fmaxf(fmaxf(fmaxf(v0, v1), fmaxf(v2, v3)), v4);
            mx = fmaxf(mx, __shfl_xor(mx, 1));
            mx = fmaxf(mx, __shfl_xor(mx, 2));
            mx = fmaxf(mx, __shfl_xor(mx, 4));
            mx = fmaxf(mx, __shfl_xor(mx, 8));
            float e0 = __expf(v0 - mx), e1 = __expf(v1 - mx);
            float e2 = __expf(v2 - mx), e3 = __expf(v3 - mx);
            float e4 = __expf(v4 - mx);
            float sum = e0 + e1 + e2 + e3 + e4;
            sum += __shfl_xor(sum, 1);
            sum += __shfl_xor(sum, 2);
            sum += __shfl_xor(sum, 4);
            sum += __shfl_xor(sum, 8);
            float inv = 1.f / sum;
            int row = t * 16 + quad * 4 + r;
            pw[row * 104 +  0 + l16] = f2bf(e0 * inv);
            pw[row * 104 + 16 + l16] = f2bf(e1 * inv);
            pw[row * 104 + 32 + l16] = f2bf(e2 * inv);
            pw[row * 104 + 48 + l16] = f2bf(e3 * inv);
            pw[row * 104 + 64 + l16] = f2bf(e4 * inv);
            pw[row * 104 + 80 + l16] = 0;
        }
    }
    // (same-wave ds_write -> ds_read ordered by lgkmcnt; LDS ops are in-order)

    // ---- PV: out[32,64] = P[32,96] @ V[96,64] ----
    floatx4 accO[2][4] = {};
    #pragma unroll
    for (int kk = 0; kk < 3; ++kk) {
        bf16x8 aw[2], bv[4];
        #pragma unroll
        for (int t = 0; t < 2; ++t)
            aw[t] = *(const bf16x8*)(&pw[(t * 16 + l16) * 104 + kk * 32 + quad * 8]);
        #pragma unroll
        for (int j = 0; j < 4; ++j)
            bv[j] = *(const bf16x8*)(&vts[(j * 16 + l16) * 104 + kk * 32 + quad * 8]);
        __builtin_amdgcn_s_setprio(1);
        #pragma unroll
        for (int t = 0; t < 2; ++t)
            #pragma unroll
            for (int j = 0; j < 4; ++j)
                accO[t][j] = __builtin_amdgcn_mfma_f32_16x16x32_bf16(
                    aw[t], bv[j], accO[t][j], 0, 0, 0);
        __builtin_amdgcn_s_setprio(0);
    }

    // ---- stage out tile into private LDS, then 16B coalesced stores ----
    #pragma unroll
    for (int t = 0; t < 2; ++t)
        #pragma unroll
        for (int j = 0; j < 4; ++j)
            #pragma unroll
            for (int r = 0; r < 4; ++r) {
                int row = t * 16 + quad * 4 + r;
                pw[row * 72 + j * 16 + l16] = f2bf(accO[t][j][r]);
            }

    u16* obase = ob + qrow * HS + h * 64;
    #pragma unroll
    for (int k = 0; k < 4; ++k) {
        int v   = k * 64 + lane;
        int row = v >> 3;
        int c8  = v & 7;
        *(uint4*)(obase + (long)row * HS + c8 * 8) =
            *(const uint4*)(&pw[row * 72 + c8 * 8]);
    }
}

// ---------------------------------------------------------------------------
extern "C" void kernel_launch(void* const* d_in, const int* in_sizes, int n_in,
                              void* d_out, int out_size, void* d_ws, size_t ws_size,
                              hipStream_t stream) {
    const float* query   = (const float*)d_in[0];  // [16,4096,512] fp32
    const float* context = (const float*)d_in[1];  // [16,77,768]   fp32
    const float* Wq      = (const float*)d_in[2];  // [512,512]     fp32
    const float* Wk      = (const float*)d_in[3];  // [768,512]     fp32
    const float* Wv      = (const float*)d_in[4];  // [768,512]     fp32
    const float* Wo      = (const float*)d_in[5];  // [512,512]     fp32
    const float* bo      = (const float*)d_in[6];  // [512]         fp32
    float* out = (float*)d_out;                    // [16,4096,512] fp32

    // workspace layout (u16 elements)
    u16* q_ws  = (u16*)d_ws;            // 16*4096*512 (also attn out, in-place)
    u16* kv_ws = q_ws + 33554432;       // 1232*1024
    u16* WqT   = kv_ws + 1261568;       // 512*512
    u16* WkvT  = WqT + 262144;          // 1024*768
    u16* WoT   = WkvT + 786432;         // 512*512

    // vt scratch lives in d_out (134 MB fp32 buffer): dead until the final
    // o-proj GEMM overwrites it, and vt is consumed by attn before that.
    // 16*8*64*96 u16 = 1.5 MB. (d_out-as-scratch proven safe in round 5.)
    u16* vt = (u16*)d_out;

    // one dispatch: three weight transposes + vt padding zero-fill
    transpose_all<<<dim3(8192), 256, 0, stream>>>(
        Wq, Wk, Wv, Wo, WqT, WkvT, WoT, vt);

    // q projection + kv projection fused in one grid: blocks [0,80) = kv
    // ([1232,768]x[768,1024]; K-half -> kv_ws, V-half scattered into vt),
    // blocks [80,1104) = q ([65536,512]x[512,512] -> q_ws).
    proj_fused<<<dim3(1104), 512, 0, stream>>>(
        query, WqT, q_ws, context, WkvT, kv_ws, vt);

    // attention, in-place on q_ws (bf16), barrier-free main body
    attn_kernel<<<dim3(16, 8, 16), 512, 0, stream>>>(q_ws, kv_ws, vt, q_ws);

    // output projection + fp32 bias: [65536,512](bf16) x [512,512] -> fp32 out
    gemm256<true><<<dim3(512), 512, 0, stream>>>(
        q_ws, WoT, (void*)out, bo, 65536, 512, 512, 1);
}